// Round 1
// baseline (1319.862 us; speedup 1.0000x reference)
//
#include <hip/hip_runtime.h>
#include <math.h>

// Problem constants (fixed by reference)
constexpr int nB = 8;
constexpr int nC = 512;
constexpr int nH = 96;
constexpr int nW = 96;
constexpr int nP = nH * nW;        // 9216 pixels per batch
constexpr int nCQK = 64;           // q/k channels
constexpr int nS = nH + nW;        // 192 softmax width

// ---------------------------------------------------------------------------
// K1: projection GEMM.  out'[b][p][o] = sum_c x[b][c][p] * Wm[o][c] + bias[o]
// Writes NHWC layout (contiguous in o) -> coalesced, and gives later kernels
// contiguous per-pixel channel vectors.
// Tile: 64p x 64o x 16c, 256 threads, 4x4 register tile.
// ---------------------------------------------------------------------------
__global__ __launch_bounds__(256) void proj_kernel(
    const float* __restrict__ x, const float* __restrict__ Wm,
    const float* __restrict__ bias, float* __restrict__ outp, int O)
{
    __shared__ float xs[16][64];   // [c][p]
    __shared__ float wt[16][64];   // [c][o]
    const int b  = blockIdx.z;
    const int p0 = blockIdx.x * 64;
    const int o0 = blockIdx.y * 64;
    const int tid = threadIdx.x;
    const int tx = tid % 16;       // o quad
    const int ty = tid / 16;       // p quad
    float acc[4][4] = {};
    const float* xb = x + (size_t)b * nC * nP;

    for (int c0 = 0; c0 < nC; c0 += 16) {
        // stage x tile (coalesced over p)
        {
            int row  = tid / 16;          // c sub 0..15
            int col4 = (tid % 16) * 4;    // p sub
            float4 xv = *(const float4*)&xb[(size_t)(c0 + row) * nP + p0 + col4];
            *(float4*)&xs[row][col4] = xv;
        }
        // stage W tile (coalesced over c), transposed into [c][o]
        {
            int o  = tid % 64;
            int k4 = (tid / 64) * 4;
            float4 wv = *(const float4*)&Wm[(size_t)(o0 + o) * nC + c0 + k4];
            wt[k4 + 0][o] = wv.x; wt[k4 + 1][o] = wv.y;
            wt[k4 + 2][o] = wv.z; wt[k4 + 3][o] = wv.w;
        }
        __syncthreads();
        #pragma unroll
        for (int kk = 0; kk < 16; ++kk) {
            float4 av = *(const float4*)&xs[kk][ty * 4];
            float4 bv = *(const float4*)&wt[kk][tx * 4];
            float a[4] = {av.x, av.y, av.z, av.w};
            float bb[4] = {bv.x, bv.y, bv.z, bv.w};
            #pragma unroll
            for (int i = 0; i < 4; ++i)
                #pragma unroll
                for (int j = 0; j < 4; ++j)
                    acc[i][j] += a[i] * bb[j];
        }
        __syncthreads();
    }
    #pragma unroll
    for (int i = 0; i < 4; ++i) {
        int p = p0 + ty * 4 + i;
        float4 r;
        r.x = acc[i][0] + bias[o0 + tx * 4 + 0];
        r.y = acc[i][1] + bias[o0 + tx * 4 + 1];
        r.z = acc[i][2] + bias[o0 + tx * 4 + 2];
        r.w = acc[i][3] + bias[o0 + tx * 4 + 3];
        *(float4*)&outp[((size_t)b * nP + p) * O + o0 + tx * 4] = r;
    }
}

// ---------------------------------------------------------------------------
// K2/K3: attention scores.
// mode 0 (H): per (b,w) block -> eH[h][g] = q[.,h,w] . k[.,g,w], diag=-inf
// mode 1 (W): per (b,h) block -> eW[w][u] = q[.,h,w] . k[.,h,u]
// 96x96 scores per block, 64-dot each.  6x6 register tile per thread.
// ---------------------------------------------------------------------------
__global__ __launch_bounds__(256) void score_kernel(
    const float* __restrict__ qp, const float* __restrict__ kp,
    float* __restrict__ att, int mode)
{
    __shared__ float Qs[96][68];
    __shared__ float Ks[96][68];
    const int b   = blockIdx.y;
    const int fix = blockIdx.x;        // w (mode 0) or h (mode 1)
    const int tid = threadIdx.x;

    for (int l = tid; l < 96 * 16; l += 256) {
        int r  = l / 16;
        int c4 = (l % 16) * 4;
        size_t p = (mode == 0) ? ((size_t)r * nW + fix) : ((size_t)fix * nW + r);
        *(float4*)&Qs[r][c4] = *(const float4*)&qp[((size_t)b * nP + p) * nCQK + c4];
        *(float4*)&Ks[r][c4] = *(const float4*)&kp[((size_t)b * nP + p) * nCQK + c4];
    }
    __syncthreads();

    const int tx = tid % 16;   // col base
    const int ty = tid / 16;   // row base
    float acc[6][6] = {};
    for (int c4 = 0; c4 < nCQK; c4 += 4) {
        float4 qv[6], kv[6];
        #pragma unroll
        for (int i = 0; i < 6; ++i) qv[i] = *(const float4*)&Qs[ty + 16 * i][c4];
        #pragma unroll
        for (int j = 0; j < 6; ++j) kv[j] = *(const float4*)&Ks[tx + 16 * j][c4];
        #pragma unroll
        for (int i = 0; i < 6; ++i)
            #pragma unroll
            for (int j = 0; j < 6; ++j)
                acc[i][j] += qv[i].x * kv[j].x + qv[i].y * kv[j].y
                           + qv[i].z * kv[j].z + qv[i].w * kv[j].w;
    }

    #pragma unroll
    for (int i = 0; i < 6; ++i) {
        int row = ty + 16 * i;
        #pragma unroll
        for (int j = 0; j < 6; ++j) {
            int col = tx + 16 * j;
            float val = acc[i][j];
            if (mode == 0) {
                if (col == row) val = -INFINITY;         // diag mask on eH
                att[((size_t)b * nP + row * nW + fix) * nS + col] = val;
            } else {
                att[((size_t)b * nP + fix * nW + row) * nS + 96 + col] = val;
            }
        }
    }
}

// ---------------------------------------------------------------------------
// K4: softmax over 192 entries per pixel, in place.  One wave per pixel.
// ---------------------------------------------------------------------------
__global__ __launch_bounds__(256) void softmax_kernel(float* __restrict__ att)
{
    const int wav  = threadIdx.x / 64;
    const int lane = threadIdx.x % 64;
    const size_t pix = (size_t)blockIdx.x * 4 + wav;
    float* a = att + pix * nS;
    float v0 = a[lane], v1 = a[lane + 64], v2 = a[lane + 128];
    float m = fmaxf(fmaxf(v0, v1), v2);
    #pragma unroll
    for (int off = 32; off; off >>= 1) m = fmaxf(m, __shfl_xor(m, off));
    float e0 = __expf(v0 - m), e1 = __expf(v1 - m), e2 = __expf(v2 - m);
    float s = e0 + e1 + e2;
    #pragma unroll
    for (int off = 32; off; off >>= 1) s += __shfl_xor(s, off);
    float inv = 1.0f / s;
    a[lane] = e0 * inv; a[lane + 64] = e1 * inv; a[lane + 128] = e2 * inv;
}

// ---------------------------------------------------------------------------
// K5: out_H'[b][p(h,w)][c] = sum_g aH[h,w,g] * v'[b][p(g,w)][c]
// One block per (b,w).  aH column slab in LDS, v' streamed in 64c tiles.
// Writes NHWC (coalesced over c).
// ---------------------------------------------------------------------------
__global__ __launch_bounds__(256) void aggH_kernel(
    const float* __restrict__ att, const float* __restrict__ vp,
    float* __restrict__ oh)
{
    __shared__ float A[96][97];     // A[h][g]
    __shared__ float Vs[96][68];    // Vs[g][c]
    const int b = blockIdx.y, w = blockIdx.x, tid = threadIdx.x;

    for (int l = tid; l < 96 * 96; l += 256) {
        int h = l / 96, g = l % 96;
        A[h][g] = att[((size_t)b * nP + h * nW + w) * nS + g];
    }
    const int tx = tid % 8;    // c octet
    const int ty = tid / 8;    // h: ty, ty+32, ty+64

    for (int c0 = 0; c0 < nC; c0 += 64) {
        __syncthreads();
        for (int l = tid; l < 96 * 16; l += 256) {
            int g = l / 16, c4 = (l % 16) * 4;
            *(float4*)&Vs[g][c4] =
                *(const float4*)&vp[((size_t)b * nP + g * nW + w) * nC + c0 + c4];
        }
        __syncthreads();
        float acc[3][8] = {};
        for (int g = 0; g < 96; ++g) {
            float4 v0 = *(const float4*)&Vs[g][tx * 8];
            float4 v1 = *(const float4*)&Vs[g][tx * 8 + 4];
            #pragma unroll
            for (int i = 0; i < 3; ++i) {
                float ag = A[ty + 32 * i][g];
                acc[i][0] += ag * v0.x; acc[i][1] += ag * v0.y;
                acc[i][2] += ag * v0.z; acc[i][3] += ag * v0.w;
                acc[i][4] += ag * v1.x; acc[i][5] += ag * v1.y;
                acc[i][6] += ag * v1.z; acc[i][7] += ag * v1.w;
            }
        }
        #pragma unroll
        for (int i = 0; i < 3; ++i) {
            int h = ty + 32 * i;
            float4 s0 = make_float4(acc[i][0], acc[i][1], acc[i][2], acc[i][3]);
            float4 s1 = make_float4(acc[i][4], acc[i][5], acc[i][6], acc[i][7]);
            size_t base = ((size_t)b * nP + h * nW + w) * nC + c0 + tx * 8;
            *(float4*)&oh[base]     = s0;
            *(float4*)&oh[base + 4] = s1;
        }
    }
}

// ---------------------------------------------------------------------------
// K6: out_W + epilogue.  One block per (b,h).
// OW[w][c] = sum_u aW[h,w,u] * v'[b][p(h,u)][c]
// out[b][c][h][w] = gamma*(OW + OH) + x   (OH staged via LDS for NHWC->NCHW)
// ---------------------------------------------------------------------------
__global__ __launch_bounds__(256) void aggW_kernel(
    const float* __restrict__ att, const float* __restrict__ vp,
    const float* __restrict__ oh, const float* __restrict__ x,
    const float* __restrict__ gamma, float* __restrict__ out)
{
    __shared__ float A[96][97];     // A[w][u]
    __shared__ float Vs[96][68];    // Vs[u][c], reused as OHs[w][c]
    const int b = blockIdx.y, h = blockIdx.x, tid = threadIdx.x;
    const float gm = gamma[0];

    for (int l = tid; l < 96 * 96; l += 256) {
        int w = l / 96, u = l % 96;
        A[w][u] = att[((size_t)b * nP + h * nW + w) * nS + 96 + u];
    }
    const int tx = tid % 32;   // w: tx, tx+32, tx+64
    const int ty = tid / 32;   // c octet: c0 + ty*8 ..

    for (int c0 = 0; c0 < nC; c0 += 64) {
        __syncthreads();
        for (int l = tid; l < 96 * 16; l += 256) {
            int u = l / 16, c4 = (l % 16) * 4;
            *(float4*)&Vs[u][c4] =
                *(const float4*)&vp[((size_t)b * nP + h * nW + u) * nC + c0 + c4];
        }
        __syncthreads();
        float acc[3][8] = {};
        for (int u = 0; u < 96; ++u) {
            float4 v0 = *(const float4*)&Vs[u][ty * 8];
            float4 v1 = *(const float4*)&Vs[u][ty * 8 + 4];
            #pragma unroll
            for (int j = 0; j < 3; ++j) {
                float aw = A[tx + 32 * j][u];
                acc[j][0] += aw * v0.x; acc[j][1] += aw * v0.y;
                acc[j][2] += aw * v0.z; acc[j][3] += aw * v0.w;
                acc[j][4] += aw * v1.x; acc[j][5] += aw * v1.y;
                acc[j][6] += aw * v1.z; acc[j][7] += aw * v1.w;
            }
        }
        __syncthreads();
        // stage OH tile (coalesced read over c), overwriting Vs
        for (int l = tid; l < 96 * 16; l += 256) {
            int w = l / 16, c4 = (l % 16) * 4;
            *(float4*)&Vs[w][c4] =
                *(const float4*)&oh[((size_t)b * nP + h * nW + w) * nC + c0 + c4];
        }
        __syncthreads();
        #pragma unroll
        for (int j = 0; j < 3; ++j) {
            int w = tx + 32 * j;
            #pragma unroll
            for (int i = 0; i < 8; ++i) {
                int c = c0 + ty * 8 + i;
                size_t oidx = ((size_t)(b * nC + c) * nH + h) * nW + w;
                float val = gm * (acc[j][i] + Vs[w][ty * 8 + i]) + x[oidx];
                out[oidx] = val;
            }
        }
    }
}

// ---------------------------------------------------------------------------
extern "C" void kernel_launch(void* const* d_in, const int* in_sizes, int n_in,
                              void* d_out, int out_size, void* d_ws, size_t ws_size,
                              hipStream_t stream)
{
    const float* x     = (const float*)d_in[0];
    const float* Wq    = (const float*)d_in[1];
    const float* bq    = (const float*)d_in[2];
    const float* Wk    = (const float*)d_in[3];
    const float* bk    = (const float*)d_in[4];
    const float* Wv    = (const float*)d_in[5];
    const float* bv    = (const float*)d_in[6];
    const float* gamma = (const float*)d_in[7];
    float* out = (float*)d_out;

    float* ws  = (float*)d_ws;
    float* qp  = ws;                                   // [B][P][64]
    float* kp  = qp + (size_t)nB * nP * nCQK;          // [B][P][64]
    float* vp  = kp + (size_t)nB * nP * nCQK;          // [B][P][512]
    float* att = vp + (size_t)nB * nP * nC;            // [B][P][192]
    float* oh  = att + (size_t)nB * nP * nS;           // [B][P][512]

    dim3 blk(256);
    proj_kernel<<<dim3(nP / 64, nCQK / 64, nB), blk, 0, stream>>>(x, Wq, bq, qp, nCQK);
    proj_kernel<<<dim3(nP / 64, nCQK / 64, nB), blk, 0, stream>>>(x, Wk, bk, kp, nCQK);
    proj_kernel<<<dim3(nP / 64, nC / 64, nB), blk, 0, stream>>>(x, Wv, bv, vp, nC);
    score_kernel<<<dim3(nW, nB), blk, 0, stream>>>(qp, kp, att, 0);
    score_kernel<<<dim3(nH, nB), blk, 0, stream>>>(qp, kp, att, 1);
    softmax_kernel<<<dim3(nB * nP / 4), blk, 0, stream>>>(att);
    aggH_kernel<<<dim3(nW, nB), blk, 0, stream>>>(att, vp, oh);
    aggW_kernel<<<dim3(nH, nB), blk, 0, stream>>>(att, vp, oh, x, gamma, out);
}

// Round 2
// 812.356 us; speedup vs baseline: 1.6247x; 1.6247x over previous
//
#include <hip/hip_runtime.h>
#include <math.h>

// Problem constants (fixed by reference)
constexpr int nB = 8;
constexpr int nC = 512;
constexpr int nH = 96;
constexpr int nW = 96;
constexpr int nP = nH * nW;        // 9216 pixels per batch
constexpr int nCQK = 64;           // q/k channels
constexpr int nS = nH + nW;        // 192 softmax width
constexpr int nO = 640;            // fused q(64)|k(64)|v(512)
constexpr int nM = nB * nP;        // 73728 total pixels

using short8  = __attribute__((ext_vector_type(8))) short;
using floatx4 = __attribute__((ext_vector_type(4))) float;

__device__ inline unsigned pack_bf16(float a, float b) {
    unsigned ua = __float_as_uint(a), ub = __float_as_uint(b);
    ua = (ua + 0x7fff + ((ua >> 16) & 1)) >> 16;   // RNE
    ub = (ub + 0x7fff + ((ub >> 16) & 1)) >> 16;
    return ua | (ub << 16);
}

// ---------------------------------------------------------------------------
// T1: x[b][c][p] fp32  ->  xT[b*nP+p][c] bf16   (64c x 64p LDS tile)
// LDS stride 65 (odd) -> conflict-free transposed reads; scalar LDS writes.
// ---------------------------------------------------------------------------
__global__ __launch_bounds__(256) void transpose_kernel(
    const float* __restrict__ x, ushort* __restrict__ xT)
{
    __shared__ float T[64 * 65];
    const int b = blockIdx.z, p0 = blockIdx.x * 64, c0 = blockIdx.y * 64;
    const int tid = threadIdx.x;
    #pragma unroll
    for (int it = 0; it < 4; ++it) {
        int c  = it * 16 + (tid >> 4);
        int p4 = (tid & 15) * 4;
        float4 v = *(const float4*)&x[((size_t)b * nC + c0 + c) * nP + p0 + p4];
        T[c * 65 + p4 + 0] = v.x; T[c * 65 + p4 + 1] = v.y;
        T[c * 65 + p4 + 2] = v.z; T[c * 65 + p4 + 3] = v.w;
    }
    __syncthreads();
    #pragma unroll
    for (int it = 0; it < 8; ++it) {
        int idx = it * 256 + tid;
        int p = idx >> 5;              // 0..63
        int c = (idx & 31) * 2;        // even c
        unsigned u = pack_bf16(T[c * 65 + p], T[(c + 1) * 65 + p]);
        *(unsigned*)&xT[((size_t)b * nP + p0 + p) * nC + c0 + c] = u;
    }
}

// ---------------------------------------------------------------------------
// T2: weights -> bf16 Wc[640][512], bias -> bc[640]. One block per o-row.
// ---------------------------------------------------------------------------
__global__ __launch_bounds__(256) void wconv_kernel(
    const float* __restrict__ Wq, const float* __restrict__ bq,
    const float* __restrict__ Wk, const float* __restrict__ bk,
    const float* __restrict__ Wv, const float* __restrict__ bv,
    ushort* __restrict__ Wc, float* __restrict__ bc)
{
    const int o = blockIdx.x, t = threadIdx.x;
    const float *src, *bsrc; int oo;
    if (o < 64)       { src = Wq; bsrc = bq; oo = o; }
    else if (o < 128) { src = Wk; bsrc = bk; oo = o - 64; }
    else              { src = Wv; bsrc = bv; oo = o - 128; }
    float2 v = *(const float2*)&src[(size_t)oo * nC + t * 2];
    *(unsigned*)&Wc[(size_t)o * nC + t * 2] = pack_bf16(v.x, v.y);
    if (t == 0) bc[o] = bsrc[oo];
}

// ---------------------------------------------------------------------------
// G: fused QKV projection via MFMA.
// qkv[m][o] = sum_c xT[m][c]*Wc[o][c] + bc[o],  m in [0,73728), o in [0,640)
// 128x128 tile, BK=32, 4 waves 2x2, 16x16x32 bf16 MFMA, 4x4 frags/wave.
// LDS rows padded to 40 bf16 (80 B, 16B-aligned) -> 2-way-free b128 access.
// ---------------------------------------------------------------------------
__global__ __launch_bounds__(256) void mfma_proj_kernel(
    const ushort* __restrict__ xT, const ushort* __restrict__ Wc,
    const float* __restrict__ bc, float* __restrict__ qkv)
{
    __shared__ ushort As[128 * 40];
    __shared__ ushort Bs[128 * 40];
    const int tid = threadIdx.x;
    const int m0 = blockIdx.x * 128;
    const int o0 = blockIdx.y * 128;

    // staging: thread covers (row sm, 16B k-part skp) and (+64 rows)
    const int sm  = tid >> 2;          // 0..63
    const int skp = tid & 3;           // 0..3
    const ushort* pa0 = xT + (size_t)(m0 + sm) * nC + skp * 8;
    const ushort* pa1 = xT + (size_t)(m0 + sm + 64) * nC + skp * 8;
    const ushort* pb0 = Wc + (size_t)(o0 + sm) * nC + skp * 8;
    const ushort* pb1 = Wc + (size_t)(o0 + sm + 64) * nC + skp * 8;
    ushort* la0 = &As[sm * 40 + skp * 8];
    ushort* la1 = &As[(sm + 64) * 40 + skp * 8];
    ushort* lb0 = &Bs[sm * 40 + skp * 8];
    ushort* lb1 = &Bs[(sm + 64) * 40 + skp * 8];

    // fragment read offsets (verified m89 layout: row = sub + (lane&15), k = (lane>>4)*8 + j)
    const int lane = tid & 63;
    const int wave = tid >> 6;
    const int wr = wave & 1, wcl = wave >> 1;
    const int lm = lane & 15, q = lane >> 4;
    int aoff[4], boff[4];
    #pragma unroll
    for (int i = 0; i < 4; ++i) aoff[i] = (wr * 64 + i * 16 + lm) * 40 + q * 8;
    #pragma unroll
    for (int j = 0; j < 4; ++j) boff[j] = (wcl * 64 + j * 16 + lm) * 40 + q * 8;

    floatx4 acc[4][4];
    #pragma unroll
    for (int i = 0; i < 4; ++i)
        #pragma unroll
        for (int j = 0; j < 4; ++j) acc[i][j] = (floatx4){0.f, 0.f, 0.f, 0.f};

    for (int k0 = 0; k0 < nC; k0 += 32) {
        uint4 a0 = *(const uint4*)(pa0 + k0);
        uint4 a1 = *(const uint4*)(pa1 + k0);
        uint4 b0 = *(const uint4*)(pb0 + k0);
        uint4 b1 = *(const uint4*)(pb1 + k0);
        if (k0) __syncthreads();
        *(uint4*)la0 = a0; *(uint4*)la1 = a1;
        *(uint4*)lb0 = b0; *(uint4*)lb1 = b1;
        __syncthreads();
        short8 av[4], bv[4];
        #pragma unroll
        for (int i = 0; i < 4; ++i) av[i] = *(const short8*)&As[aoff[i]];
        #pragma unroll
        for (int j = 0; j < 4; ++j) bv[j] = *(const short8*)&Bs[boff[j]];
        #pragma unroll
        for (int i = 0; i < 4; ++i)
            #pragma unroll
            for (int j = 0; j < 4; ++j)
                acc[i][j] = __builtin_amdgcn_mfma_f32_16x16x32_bf16(
                    av[i], bv[j], acc[i][j], 0, 0, 0);
    }

    // epilogue: C/D layout col = lane&15, row = q*4 + r (verified m89)
    float bj[4];
    #pragma unroll
    for (int j = 0; j < 4; ++j) bj[j] = bc[o0 + wcl * 64 + j * 16 + lm];
    #pragma unroll
    for (int i = 0; i < 4; ++i) {
        #pragma unroll
        for (int r = 0; r < 4; ++r) {
            int mrow = m0 + wr * 64 + i * 16 + q * 4 + r;
            float* orow = qkv + (size_t)mrow * nO + o0 + wcl * 64 + lm;
            #pragma unroll
            for (int j = 0; j < 4; ++j) orow[j * 16] = acc[i][j][r] + bj[j];
        }
    }
}

// ---------------------------------------------------------------------------
// scores: mode 0 (H): per (b,w) -> eH[h][g], diag=-inf ; mode 1 (W): per (b,h)
// q/k rows read from fused qkv (stride nO, offsets 0 / 64).
// ---------------------------------------------------------------------------
__global__ __launch_bounds__(256) void score_kernel(
    const float* __restrict__ qkv, float* __restrict__ att, int mode)
{
    __shared__ float Qs[96][68];
    __shared__ float Ks[96][68];
    const int b   = blockIdx.y;
    const int fix = blockIdx.x;
    const int tid = threadIdx.x;

    for (int l = tid; l < 96 * 16; l += 256) {
        int r  = l / 16;
        int c4 = (l % 16) * 4;
        size_t p = (mode == 0) ? ((size_t)r * nW + fix) : ((size_t)fix * nW + r);
        const float* row = &qkv[((size_t)b * nP + p) * nO];
        *(float4*)&Qs[r][c4] = *(const float4*)&row[c4];
        *(float4*)&Ks[r][c4] = *(const float4*)&row[64 + c4];
    }
    __syncthreads();

    const int tx = tid % 16;
    const int ty = tid / 16;
    float acc[6][6] = {};
    for (int c4 = 0; c4 < nCQK; c4 += 4) {
        float4 qv[6], kv[6];
        #pragma unroll
        for (int i = 0; i < 6; ++i) qv[i] = *(const float4*)&Qs[ty + 16 * i][c4];
        #pragma unroll
        for (int j = 0; j < 6; ++j) kv[j] = *(const float4*)&Ks[tx + 16 * j][c4];
        #pragma unroll
        for (int i = 0; i < 6; ++i)
            #pragma unroll
            for (int j = 0; j < 6; ++j)
                acc[i][j] += qv[i].x * kv[j].x + qv[i].y * kv[j].y
                           + qv[i].z * kv[j].z + qv[i].w * kv[j].w;
    }

    #pragma unroll
    for (int i = 0; i < 6; ++i) {
        int row = ty + 16 * i;
        #pragma unroll
        for (int j = 0; j < 6; ++j) {
            int col = tx + 16 * j;
            float val = acc[i][j];
            if (mode == 0) {
                if (col == row) val = -INFINITY;
                att[((size_t)b * nP + row * nW + fix) * nS + col] = val;
            } else {
                att[((size_t)b * nP + fix * nW + row) * nS + 96 + col] = val;
            }
        }
    }
}

// ---------------------------------------------------------------------------
// softmax over 192 entries per pixel, in place. One wave per pixel.
// ---------------------------------------------------------------------------
__global__ __launch_bounds__(256) void softmax_kernel(float* __restrict__ att)
{
    const int wav  = threadIdx.x / 64;
    const int lane = threadIdx.x % 64;
    const size_t pix = (size_t)blockIdx.x * 4 + wav;
    float* a = att + pix * nS;
    float v0 = a[lane], v1 = a[lane + 64], v2 = a[lane + 128];
    float m = fmaxf(fmaxf(v0, v1), v2);
    #pragma unroll
    for (int off = 32; off; off >>= 1) m = fmaxf(m, __shfl_xor(m, off));
    float e0 = __expf(v0 - m), e1 = __expf(v1 - m), e2 = __expf(v2 - m);
    float s = e0 + e1 + e2;
    #pragma unroll
    for (int off = 32; off; off >>= 1) s += __shfl_xor(s, off);
    float inv = 1.0f / s;
    a[lane] = e0 * inv; a[lane + 64] = e1 * inv; a[lane + 128] = e2 * inv;
}

// ---------------------------------------------------------------------------
// aggH: oh[b][p(h,w)][c] = sum_g aH[h,w,g] * v[b][p(g,w)][c]   (v from qkv+128)
// ---------------------------------------------------------------------------
__global__ __launch_bounds__(256) void aggH_kernel(
    const float* __restrict__ att, const float* __restrict__ qkv,
    float* __restrict__ oh)
{
    __shared__ float A[96][97];
    __shared__ float Vs[96][68];
    const int b = blockIdx.y, w = blockIdx.x, tid = threadIdx.x;

    for (int l = tid; l < 96 * 96; l += 256) {
        int h = l / 96, g = l % 96;
        A[h][g] = att[((size_t)b * nP + h * nW + w) * nS + g];
    }
    const int tx = tid % 8;
    const int ty = tid / 8;

    for (int c0 = 0; c0 < nC; c0 += 64) {
        __syncthreads();
        for (int l = tid; l < 96 * 16; l += 256) {
            int g = l / 16, c4 = (l % 16) * 4;
            *(float4*)&Vs[g][c4] =
                *(const float4*)&qkv[((size_t)b * nP + g * nW + w) * nO + 128 + c0 + c4];
        }
        __syncthreads();
        float acc[3][8] = {};
        for (int g = 0; g < 96; ++g) {
            float4 v0 = *(const float4*)&Vs[g][tx * 8];
            float4 v1 = *(const float4*)&Vs[g][tx * 8 + 4];
            #pragma unroll
            for (int i = 0; i < 3; ++i) {
                float ag = A[ty + 32 * i][g];
                acc[i][0] += ag * v0.x; acc[i][1] += ag * v0.y;
                acc[i][2] += ag * v0.z; acc[i][3] += ag * v0.w;
                acc[i][4] += ag * v1.x; acc[i][5] += ag * v1.y;
                acc[i][6] += ag * v1.z; acc[i][7] += ag * v1.w;
            }
        }
        #pragma unroll
        for (int i = 0; i < 3; ++i) {
            int h = ty + 32 * i;
            float4 s0 = make_float4(acc[i][0], acc[i][1], acc[i][2], acc[i][3]);
            float4 s1 = make_float4(acc[i][4], acc[i][5], acc[i][6], acc[i][7]);
            size_t base = ((size_t)b * nP + h * nW + w) * nC + c0 + tx * 8;
            *(float4*)&oh[base]     = s0;
            *(float4*)&oh[base + 4] = s1;
        }
    }
}

// ---------------------------------------------------------------------------
// aggW + epilogue: OW[w][c] = sum_u aW[h,w,u]*v[b][p(h,u)][c];
// out = gamma*(OW+OH) + x  (NCHW, OH staged through LDS)
// ---------------------------------------------------------------------------
__global__ __launch_bounds__(256) void aggW_kernel(
    const float* __restrict__ att, const float* __restrict__ qkv,
    const float* __restrict__ oh, const float* __restrict__ x,
    const float* __restrict__ gamma, float* __restrict__ out)
{
    __shared__ float A[96][97];
    __shared__ float Vs[96][68];
    const int b = blockIdx.y, h = blockIdx.x, tid = threadIdx.x;
    const float gm = gamma[0];

    for (int l = tid; l < 96 * 96; l += 256) {
        int w = l / 96, u = l % 96;
        A[w][u] = att[((size_t)b * nP + h * nW + w) * nS + 96 + u];
    }
    const int tx = tid % 32;
    const int ty = tid / 32;

    for (int c0 = 0; c0 < nC; c0 += 64) {
        __syncthreads();
        for (int l = tid; l < 96 * 16; l += 256) {
            int u = l / 16, c4 = (l % 16) * 4;
            *(float4*)&Vs[u][c4] =
                *(const float4*)&qkv[((size_t)b * nP + h * nW + u) * nO + 128 + c0 + c4];
        }
        __syncthreads();
        float acc[3][8] = {};
        for (int u = 0; u < 96; ++u) {
            float4 v0 = *(const float4*)&Vs[u][ty * 8];
            float4 v1 = *(const float4*)&Vs[u][ty * 8 + 4];
            #pragma unroll
            for (int j = 0; j < 3; ++j) {
                float aw = A[tx + 32 * j][u];
                acc[j][0] += aw * v0.x; acc[j][1] += aw * v0.y;
                acc[j][2] += aw * v0.z; acc[j][3] += aw * v0.w;
                acc[j][4] += aw * v1.x; acc[j][5] += aw * v1.y;
                acc[j][6] += aw * v1.z; acc[j][7] += aw * v1.w;
            }
        }
        __syncthreads();
        for (int l = tid; l < 96 * 16; l += 256) {
            int w = l / 16, c4 = (l % 16) * 4;
            *(float4*)&Vs[w][c4] =
                *(const float4*)&oh[((size_t)b * nP + h * nW + w) * nC + c0 + c4];
        }
        __syncthreads();
        #pragma unroll
        for (int j = 0; j < 3; ++j) {
            int w = tx + 32 * j;
            #pragma unroll
            for (int i = 0; i < 8; ++i) {
                int c = c0 + ty * 8 + i;
                size_t oidx = ((size_t)(b * nC + c) * nH + h) * nW + w;
                out[oidx] = gm * (acc[j][i] + Vs[w][ty * 8 + i]) + x[oidx];
            }
        }
    }
}

// ---------------------------------------------------------------------------
extern "C" void kernel_launch(void* const* d_in, const int* in_sizes, int n_in,
                              void* d_out, int out_size, void* d_ws, size_t ws_size,
                              hipStream_t stream)
{
    const float* x     = (const float*)d_in[0];
    const float* Wq    = (const float*)d_in[1];
    const float* bq    = (const float*)d_in[2];
    const float* Wk    = (const float*)d_in[3];
    const float* bk    = (const float*)d_in[4];
    const float* Wv    = (const float*)d_in[5];
    const float* bv    = (const float*)d_in[6];
    const float* gamma = (const float*)d_in[7];
    float* out = (float*)d_out;

    // Workspace layout (fits round-1 footprint, 396.4 MB):
    //   region1 [nM*nC floats]: xT (bf16, first half) until proj done, then oh
    //   qkv     [nM*nO floats]
    //   att     [nM*nS floats]: Wc+bc (bf16 weights) until scores run, then att
    float* ws  = (float*)d_ws;
    float*  oh  = ws;
    ushort* xT  = (ushort*)ws;
    float*  qkv = ws + (size_t)nM * nC;
    float*  att = qkv + (size_t)nM * nO;
    ushort* Wc  = (ushort*)att;
    float*  bc  = att + (size_t)nO * nC / 2;   // after 640*512 ushorts

    dim3 blk(256);
    transpose_kernel<<<dim3(nP / 64, nC / 64, nB), blk, 0, stream>>>(x, xT);
    wconv_kernel<<<dim3(nO), blk, 0, stream>>>(Wq, bq, Wk, bk, Wv, bv, Wc, bc);
    mfma_proj_kernel<<<dim3(nM / 128, nO / 128), blk, 0, stream>>>(xT, Wc, bc, qkv);
    score_kernel<<<dim3(nW, nB), blk, 0, stream>>>(qkv, att, 0);
    score_kernel<<<dim3(nH, nB), blk, 0, stream>>>(qkv, att, 1);
    softmax_kernel<<<dim3(nB * nP / 4), blk, 0, stream>>>(att);
    aggH_kernel<<<dim3(nW, nB), blk, 0, stream>>>(att, qkv, oh);
    aggW_kernel<<<dim3(nH, nB), blk, 0, stream>>>(att, qkv, oh, x, gamma, out);
}